// Round 5
// baseline (843.121 us; speedup 1.0000x reference)
//
#include <hip/hip_runtime.h>
#include <hip/hip_bf16.h>

typedef unsigned short u16;
typedef __bf16 bf16x8 __attribute__((ext_vector_type(8)));
typedef float f32x4 __attribute__((ext_vector_type(4)));
typedef u16 ushort8 __attribute__((ext_vector_type(8)));

#define TSEQ 2048
#define NHEAD 16

static __device__ __forceinline__ float bf2f(u16 u) {
  unsigned int x = ((unsigned int)u) << 16;
  union { unsigned int i; float f; } c; c.i = x; return c.f;
}
static __device__ __forceinline__ u16 f2bf(float f) {
  union { float f; unsigned int i; } c; c.f = f;
  unsigned int x = c.i;
  unsigned int r = (x + 0x7FFFu + ((x >> 16) & 1u)) >> 16;
  return (u16)r;
}
static __device__ __forceinline__ void st_out(u16* p, float v) { *p = f2bf(v); }
static __device__ __forceinline__ void st_out(float* p, float v) { *p = v; }

// ---------------- convert x (f32 -> bf16), 8 elems/thread ----------------
__global__ __launch_bounds__(256) void k_conv_x(const float* __restrict__ x, u16* __restrict__ xb) {
  size_t i = ((size_t)blockIdx.x * 256 + threadIdx.x) * 8;
  float4 a = *(const float4*)(x + i);
  float4 b = *(const float4*)(x + i + 4);
  ushort8 o;
  o[0] = f2bf(a.x); o[1] = f2bf(a.y); o[2] = f2bf(a.z); o[3] = f2bf(a.w);
  o[4] = f2bf(b.x); o[5] = f2bf(b.y); o[6] = f2bf(b.z); o[7] = f2bf(b.w);
  *(ushort8*)(xb + i) = o;
}

// -------- transpose+convert weight: src f32 [R,Cc] -> dst bf16 [Cpad][Rpad], dst[c][r]=src[r][c] (0 pad) --------
__global__ __launch_bounds__(256) void k_tconv(const float* __restrict__ src, u16* __restrict__ dst,
                                               int R, int Cc, int Rpad) {
  __shared__ float sm[32][33];
  int tx = threadIdx.x & 31, ty = threadIdx.x >> 5;
  int r0 = blockIdx.x * 32, c0 = blockIdx.y * 32;
#pragma unroll
  for (int i = 0; i < 4; i++) {
    int r = r0 + ty + 8 * i;
    int c = c0 + tx;
    sm[ty + 8 * i][tx] = (r < R && c < Cc) ? src[(size_t)r * Cc + c] : 0.f;
  }
  __syncthreads();
#pragma unroll
  for (int i = 0; i < 4; i++) {
    int c = c0 + ty + 8 * i;
    dst[(size_t)c * Rpad + r0 + tx] = f2bf(sm[tx][ty + 8 * i]);
  }
}

// ---------------- gate = 2*sigmoid(x[:, :32] @ w_ve_gate) ----------------
__global__ __launch_bounds__(256) void k_gate(const float* __restrict__ x, const float* __restrict__ wg,
                                              float* __restrict__ gate) {
  int idx = blockIdx.x * 256 + threadIdx.x; // m*16 + h
  int m = idx >> 4, h = idx & 15;
  const float* xr = x + (size_t)m * 2048;
  float s = 0.f;
#pragma unroll
  for (int j = 0; j < 32; j++) s += xr[j] * wg[j * 16 + h];
  gate[idx] = 2.f / (1.f + __expf(-s));
}

// ---------------- generic GEMM: C[M,N] = A[M,K] @ BT[N,K]^T, bf16 in, f32 accum, OT out ----------------
template <typename OT>
__global__ __launch_bounds__(256) void k_gemm_bt(const u16* __restrict__ A, const u16* __restrict__ BT,
                                                 OT* __restrict__ C, int M, int N, int K) {
  __shared__ __align__(16) u16 As[64][40];
  __shared__ __align__(16) u16 Bs[64][40];
  int t = threadIdx.x;
  int wid = t >> 6, lane = t & 63;
  int wr = (wid >> 1) * 32, wc = (wid & 1) * 32;
  int m0 = blockIdx.y * 64, n0 = blockIdx.x * 64;
  int lrow = t >> 2, lk = (t & 3) * 8;
  const u16* Ag = A + (size_t)(m0 + lrow) * K + lk;
  const u16* Bg = BT + (size_t)(n0 + lrow) * K + lk;
  f32x4 acc00 = {0,0,0,0}, acc01 = {0,0,0,0}, acc10 = {0,0,0,0}, acc11 = {0,0,0,0};
  int fr = lane & 15, fo = (lane >> 4) * 8;
  for (int k0 = 0; k0 < K; k0 += 32) {
    *(ushort8*)&As[lrow][lk] = *(const ushort8*)(Ag + k0);
    *(ushort8*)&Bs[lrow][lk] = *(const ushort8*)(Bg + k0);
    __syncthreads();
    bf16x8 a0 = *(const bf16x8*)&As[wr + fr][fo];
    bf16x8 a1 = *(const bf16x8*)&As[wr + 16 + fr][fo];
    bf16x8 b0 = *(const bf16x8*)&Bs[wc + fr][fo];
    bf16x8 b1 = *(const bf16x8*)&Bs[wc + 16 + fr][fo];
    acc00 = __builtin_amdgcn_mfma_f32_16x16x32_bf16(a0, b0, acc00, 0, 0, 0);
    acc01 = __builtin_amdgcn_mfma_f32_16x16x32_bf16(a0, b1, acc01, 0, 0, 0);
    acc10 = __builtin_amdgcn_mfma_f32_16x16x32_bf16(a1, b0, acc10, 0, 0, 0);
    acc11 = __builtin_amdgcn_mfma_f32_16x16x32_bf16(a1, b1, acc11, 0, 0, 0);
    __syncthreads();
  }
  int cr = (lane >> 4) * 4, cc = lane & 15;
#pragma unroll
  for (int r = 0; r < 4; r++) {
    size_t row0 = (size_t)(m0 + wr + cr + r);
    size_t row1 = row0 + 16;
    st_out(&C[row0 * N + n0 + wc + cc],      acc00[r]);
    st_out(&C[row0 * N + n0 + wc + 16 + cc], acc01[r]);
    st_out(&C[row1 * N + n0 + wc + cc],      acc10[r]);
    st_out(&C[row1 * N + n0 + wc + 16 + cc], acc11[r]);
  }
}

// ---------------- build K: concat(k_nope, rope(k_rope)), rmsnorm, -> kf[b][h][t][128] bf16 ----------------
__global__ __launch_bounds__(256) void k_build_k(const u16* __restrict__ kv, const u16* __restrict__ kr,
                                                 const float* __restrict__ cosp, const float* __restrict__ sinp,
                                                 u16* __restrict__ kf) {
  int wid = threadIdx.x >> 6, lane = threadIdx.x & 63;
  int idx = blockIdx.x * 4 + wid; // m*16 + h
  int m = idx >> 4, h = idx & 15;
  int d0 = lane * 2;
  float v[2];
#pragma unroll
  for (int e = 0; e < 2; e++) {
    int d = d0 + e;
    float val;
    if (d < 64) {
      val = bf2f(kv[(size_t)m * 3072 + h * 192 + d]);
    } else {
      int dd = d - 64, i = dd & 31;
      float c = cosp[m * 32 + i], s = sinp[m * 32 + i];
      float x1 = bf2f(kr[(size_t)m * 64 + i]), x2 = bf2f(kr[(size_t)m * 64 + 32 + i]);
      val = (dd < 32) ? (x1 * c + x2 * s) : (x2 * c - x1 * s);
    }
    v[e] = val;
  }
  float ss = v[0] * v[0] + v[1] * v[1];
#pragma unroll
  for (int o = 1; o < 64; o <<= 1) ss += __shfl_xor(ss, o, 64);
  float rms = rsqrtf(ss * (1.f / 128.f) + 1.1920929e-7f);
  int b = m >> 11, tt = m & 2047;
  size_t base = ((size_t)(b * NHEAD + h) * TSEQ + tt) * 128 + d0;
  kf[base] = f2bf(v[0] * rms);
  kf[base + 1] = f2bf(v[1] * rms);
}

// ---------------- build Q: concat(q_nope, rope(q_rope)), rmsnorm, -> qf[b][h][t][128] bf16 ----------------
__global__ __launch_bounds__(256) void k_build_q(const u16* __restrict__ qr,
                                                 const float* __restrict__ cosp, const float* __restrict__ sinp,
                                                 u16* __restrict__ qf) {
  int wid = threadIdx.x >> 6, lane = threadIdx.x & 63;
  int idx = blockIdx.x * 4 + wid; // m*16 + h
  int m = idx >> 4, h = idx & 15;
  size_t bin = (size_t)m * 2048 + h * 128;
  int d0 = lane * 2;
  float v[2];
#pragma unroll
  for (int e = 0; e < 2; e++) {
    int d = d0 + e;
    float val;
    if (d < 64) {
      val = bf2f(qr[bin + d]);
    } else {
      int dd = d - 64, i = dd & 31;
      float c = cosp[m * 32 + i], s = sinp[m * 32 + i];
      float x1 = bf2f(qr[bin + 64 + i]), x2 = bf2f(qr[bin + 96 + i]);
      val = (dd < 32) ? (x1 * c + x2 * s) : (x2 * c - x1 * s);
    }
    v[e] = val;
  }
  float ss = v[0] * v[0] + v[1] * v[1];
#pragma unroll
  for (int o = 1; o < 64; o <<= 1) ss += __shfl_xor(ss, o, 64);
  float rms = rsqrtf(ss * (1.f / 128.f) + 1.1920929e-7f);
  int b = m >> 11, tt = m & 2047;
  size_t base = ((size_t)(b * NHEAD + h) * TSEQ + tt) * 128 + d0;
  qf[base] = f2bf(v[0] * rms);
  qf[base + 1] = f2bf(v[1] * rms);
}

// ---------------- build V: v = kv_v + gate*ve, transpose -> vt[b][h][128][t] bf16 ----------------
__global__ __launch_bounds__(256) void k_build_v(const u16* __restrict__ kv, const float* __restrict__ ve,
                                                 const float* __restrict__ gate, u16* __restrict__ vt) {
  __shared__ __align__(16) char sm[128 * 128]; // [128 d][64 t] u16, XOR-swizzled rows
  int bh = blockIdx.x >> 5, t0 = (blockIdx.x & 31) * 64;
  int b = bh >> 4, h = bh & 15;
  int tt = threadIdx.x >> 2, dp = (threadIdx.x & 3) * 32;
  int m = b * TSEQ + t0 + tt;
  float g = gate[m * 16 + h];
  const u16* kvp = kv + (size_t)m * 3072 + h * 192 + 64 + dp;
  const float* vep = ve + (size_t)m * 2048 + h * 128 + dp;
  ushort8 kvv[4];
  float4 vev[8];
#pragma unroll
  for (int u = 0; u < 4; u++) kvv[u] = *(const ushort8*)(kvp + u * 8);
#pragma unroll
  for (int u = 0; u < 8; u++) vev[u] = *(const float4*)(vep + u * 4);
#pragma unroll
  for (int j = 0; j < 32; j++) {
    float vvf = ((const float*)&vev[j >> 2])[j & 3];
    float v = bf2f(kvv[j >> 3][j & 7]) + g * vvf;
    int row = dp + j;
    int a = row * 128 + tt * 2;
    *(u16*)(sm + (a ^ ((row & 7) << 4))) = f2bf(v);
  }
  __syncthreads();
  int d = threadIdx.x >> 1, tp = (threadIdx.x & 1) * 32;
  u16* dst = vt + ((size_t)bh * 128 + d) * TSEQ + t0 + tp;
#pragma unroll
  for (int j = 0; j < 32; j += 8) {
    int a = d * 128 + (tp + j) * 2;
    *(ushort8*)(dst + j) = *(const ushort8*)(sm + (a ^ ((d & 7) << 4)));
  }
}

// ---------------- flash attention: 1 wave per 16-row q tile, KT=64 ----------------
__global__ __launch_bounds__(256) void k_attn(const u16* __restrict__ qf, const u16* __restrict__ kf,
                                              const u16* __restrict__ vt, u16* __restrict__ y) {
  __shared__ u16 plds_all[4][1024]; // per wave: 16 rows x 64 cols (bytes: row*128 + col*2), XOR-swizzled
  int wid = threadIdx.x >> 6, lane = threadIdx.x & 63;
  u16* plds = plds_all[wid];
  int gw = blockIdx.x * 4 + wid;
  int bh = gw >> 7, qt = gw & 127;
  int q0 = qt * 16;
  const u16* qp = qf + (size_t)bh * TSEQ * 128;
  const u16* kp = kf + (size_t)bh * TSEQ * 128;
  const u16* vp = vt + (size_t)bh * 128 * TSEQ;
  int fr = lane & 15, fo = (lane >> 4) * 8;
  bf16x8 qfr[4];
#pragma unroll
  for (int kc = 0; kc < 4; kc++)
    qfr[kc] = *(const bf16x8*)(qp + (size_t)(q0 + fr) * 128 + kc * 32 + fo);
  f32x4 oacc[8];
#pragma unroll
  for (int nd = 0; nd < 8; nd++) oacc[nd] = (f32x4){0, 0, 0, 0};
  float mrow[4] = {-1e30f, -1e30f, -1e30f, -1e30f};
  float srow[4] = {0, 0, 0, 0};
  const float scale = 0.08838834764831845f; // 1/sqrt(128)
  int qgb = q0 + (lane >> 4) * 4;
  for (int kt0 = 0; kt0 <= q0 + 15; kt0 += 64) {
    f32x4 sacc[4];
#pragma unroll
    for (int s = 0; s < 4; s++) sacc[s] = (f32x4){0, 0, 0, 0};
#pragma unroll
    for (int s = 0; s < 4; s++) {
      const u16* krow = kp + (size_t)(kt0 + s * 16 + fr) * 128 + fo;
#pragma unroll
      for (int kc = 0; kc < 4; kc++) {
        bf16x8 kfr = *(const bf16x8*)(krow + kc * 32);
        sacc[s] = __builtin_amdgcn_mfma_f32_16x16x32_bf16(qfr[kc], kfr, sacc[s], 0, 0, 0);
      }
    }
    float fsc[4];
#pragma unroll
    for (int r = 0; r < 4; r++) {
      int qrow = qgb + r;
      float mx = -3e38f;
#pragma unroll
      for (int s = 0; s < 4; s++) {
        int key = kt0 + s * 16 + fr;
        float v = (key <= qrow) ? sacc[s][r] * scale : -3e38f;
        sacc[s][r] = v;
        mx = fmaxf(mx, v);
      }
#pragma unroll
      for (int o = 1; o < 16; o <<= 1) mx = fmaxf(mx, __shfl_xor(mx, o, 64));
      float mn = fmaxf(mrow[r], mx);
      float f = __expf(mrow[r] - mn);
      mrow[r] = mn;
      float rs = 0.f;
#pragma unroll
      for (int s = 0; s < 4; s++) {
        float p = __expf(sacc[s][r] - mn);
        sacc[s][r] = p;
        rs += p;
      }
#pragma unroll
      for (int o = 1; o < 16; o <<= 1) rs += __shfl_xor(rs, o, 64);
      srow[r] = srow[r] * f + rs;
      fsc[r] = f;
    }
#pragma unroll
    for (int nd = 0; nd < 8; nd++)
#pragma unroll
      for (int r = 0; r < 4; r++) oacc[nd][r] *= fsc[r];
    // P -> LDS (bf16 stored as u16, XOR-swizzled byte addressing)
    int lrb = (lane >> 4) * 4;
#pragma unroll
    for (int r = 0; r < 4; r++) {
      int row = lrb + r;
#pragma unroll
      for (int s = 0; s < 4; s++) {
        int a = row * 128 + (s * 16 + fr) * 2;
        plds[(a ^ ((row & 7) << 4)) >> 1] = f2bf(sacc[s][r]);
      }
    }
#pragma unroll
    for (int kc2 = 0; kc2 < 2; kc2++) {
      bf16x8 pa;
#pragma unroll
      for (int j = 0; j < 8; j++) {
        int a = fr * 128 + (kc2 * 32 + fo + j) * 2;
        u16 raw = plds[(a ^ ((fr & 7) << 4)) >> 1];
        union { u16 u; __bf16 b; } cv; cv.u = raw;
        pa[j] = cv.b;
      }
#pragma unroll
      for (int nd = 0; nd < 8; nd++) {
        const u16* vrow = vp + (size_t)(nd * 16 + fr) * TSEQ + kt0 + kc2 * 32 + fo;
        bf16x8 vfr = *(const bf16x8*)vrow;
        oacc[nd] = __builtin_amdgcn_mfma_f32_16x16x32_bf16(pa, vfr, oacc[nd], 0, 0, 0);
      }
    }
  }
  int b = bh >> 4, h = bh & 15;
  float inv[4];
#pragma unroll
  for (int r = 0; r < 4; r++) inv[r] = 1.f / srow[r];
#pragma unroll
  for (int nd = 0; nd < 8; nd++) {
#pragma unroll
    for (int r = 0; r < 4; r++) {
      int qrow = qgb + r;
      size_t offo = ((size_t)(b * TSEQ + qrow)) * 2048 + h * 128 + nd * 16 + fr;
      y[offo] = f2bf(oacc[nd][r] * inv[r]);
    }
  }
}

extern "C" void kernel_launch(void* const* d_in, const int* in_sizes, int n_in,
                              void* d_out, int out_size, void* d_ws, size_t ws_size,
                              hipStream_t stream) {
  (void)in_sizes; (void)n_in; (void)out_size; (void)ws_size;
  const float* x      = (const float*)d_in[0];
  const float* ve     = (const float*)d_in[1];
  const float* cosp   = (const float*)d_in[2];
  const float* sinp   = (const float*)d_in[3];
  const float* w_dkv  = (const float*)d_in[4];
  const float* w_ukv  = (const float*)d_in[5];
  const float* w_kr   = (const float*)d_in[6];
  const float* w_dq   = (const float*)d_in[7];
  const float* w_q    = (const float*)d_in[8];
  const float* w_cp   = (const float*)d_in[9];
  const float* w_vg   = (const float*)d_in[10];
  float* out = (float*)d_out;   // reference output dtype is float32

  char* ws = (char*)d_ws;
  size_t off = 0;
  auto alloc = [&](size_t bytes) -> char* {
    char* p = ws + off;
    off += (bytes + 255) & ~(size_t)255;
    return p;
  };
  u16* xb     = (u16*)alloc(4096ull * 2048 * 2);
  u16* wdkvT  = (u16*)alloc(704ull * 2048 * 2);
  u16* wukvT  = (u16*)alloc(3072ull * 704 * 2);
  u16* wkrT   = (u16*)alloc(64ull * 2048 * 2);
  u16* wdqT   = (u16*)alloc(704ull * 2048 * 2);
  u16* wqT    = (u16*)alloc(2048ull * 704 * 2);
  u16* wcpT   = (u16*)alloc(2048ull * 2048 * 2);
  u16* ckv    = (u16*)alloc(4096ull * 704 * 2);
  u16* kvb    = (u16*)alloc(4096ull * 3072 * 2);
  u16* q1b    = (u16*)alloc(4096ull * 704 * 2);
  u16* qrawb  = (u16*)alloc(4096ull * 2048 * 2);
  u16* krb    = (u16*)alloc(4096ull * 64 * 2);
  float* gateb = (float*)alloc(4096ull * 16 * 4);
  u16* qfb    = (u16*)alloc(2ull * 16 * 2048 * 128 * 2);
  u16* kfb    = (u16*)alloc(2ull * 16 * 2048 * 128 * 2);
  u16* vtb    = (u16*)alloc(2ull * 16 * 128 * 2048 * 2);
  u16* yb = xb; // alias: x_bf dead after q1/k_rope/gate GEMMs

  // 1. conversions
  k_conv_x<<<dim3(4096), dim3(256), 0, stream>>>(x, xb);
  k_tconv<<<dim3(64, 22), dim3(256), 0, stream>>>(w_dkv, wdkvT, 2048, 672, 2048);
  k_tconv<<<dim3(22, 96), dim3(256), 0, stream>>>(w_ukv, wukvT, 672, 3072, 704);
  k_tconv<<<dim3(64, 2),  dim3(256), 0, stream>>>(w_kr,  wkrT,  2048, 64, 2048);
  k_tconv<<<dim3(64, 22), dim3(256), 0, stream>>>(w_dq,  wdqT,  2048, 672, 2048);
  k_tconv<<<dim3(22, 64), dim3(256), 0, stream>>>(w_q,   wqT,   672, 2048, 704);
  k_tconv<<<dim3(64, 64), dim3(256), 0, stream>>>(w_cp,  wcpT,  2048, 2048, 2048);
  k_gate<<<dim3(256), dim3(256), 0, stream>>>(x, w_vg, gateb);

  // 2. projection GEMMs (bf16 out)
  k_gemm_bt<u16><<<dim3(11, 64), dim3(256), 0, stream>>>(xb,  wdkvT, ckv,   4096, 704, 2048);
  k_gemm_bt<u16><<<dim3(48, 64), dim3(256), 0, stream>>>(ckv, wukvT, kvb,   4096, 3072, 704);
  k_gemm_bt<u16><<<dim3(1, 64),  dim3(256), 0, stream>>>(xb,  wkrT,  krb,   4096, 64, 2048);
  k_gemm_bt<u16><<<dim3(11, 64), dim3(256), 0, stream>>>(xb,  wdqT,  q1b,   4096, 704, 2048);
  k_gemm_bt<u16><<<dim3(32, 64), dim3(256), 0, stream>>>(q1b, wqT,   qrawb, 4096, 2048, 704);

  // 3. build q/k/v
  k_build_k<<<dim3(16384), dim3(256), 0, stream>>>(kvb, krb, cosp, sinp, kfb);
  k_build_q<<<dim3(16384), dim3(256), 0, stream>>>(qrawb, cosp, sinp, qfb);
  k_build_v<<<dim3(1024), dim3(256), 0, stream>>>(kvb, ve, gateb, vtb);

  // 4. attention -> y (aliases xb)
  k_attn<<<dim3(1024), dim3(256), 0, stream>>>(qfb, kfb, vtb, yb);

  // 5. output projection (f32 out -> d_out)
  k_gemm_bt<float><<<dim3(32, 64), dim3(256), 0, stream>>>(yb, wcpT, out, 4096, 2048, 2048);
}

// Round 6
// 598.018 us; speedup vs baseline: 1.4099x; 1.4099x over previous
//
#include <hip/hip_runtime.h>
#include <hip/hip_bf16.h>

typedef unsigned short u16;
typedef __bf16 bf16x8 __attribute__((ext_vector_type(8)));
typedef float f32x4 __attribute__((ext_vector_type(4)));
typedef u16 ushort8 __attribute__((ext_vector_type(8)));

#define TSEQ 2048
#define NHEAD 16

static __device__ __forceinline__ float bf2f(u16 u) {
  unsigned int x = ((unsigned int)u) << 16;
  union { unsigned int i; float f; } c; c.i = x; return c.f;
}
static __device__ __forceinline__ u16 f2bf(float f) {
  union { float f; unsigned int i; } c; c.f = f;
  unsigned int x = c.i;
  unsigned int r = (x + 0x7FFFu + ((x >> 16) & 1u)) >> 16;
  return (u16)r;
}
static __device__ __forceinline__ void st_out(u16* p, float v) { *p = f2bf(v); }
static __device__ __forceinline__ void st_out(float* p, float v) { *p = v; }

// ---------------- convert x (f32 -> bf16), 8 elems/thread ----------------
__global__ __launch_bounds__(256) void k_conv_x(const float* __restrict__ x, u16* __restrict__ xb) {
  size_t i = ((size_t)blockIdx.x * 256 + threadIdx.x) * 8;
  float4 a = *(const float4*)(x + i);
  float4 b = *(const float4*)(x + i + 4);
  ushort8 o;
  o[0] = f2bf(a.x); o[1] = f2bf(a.y); o[2] = f2bf(a.z); o[3] = f2bf(a.w);
  o[4] = f2bf(b.x); o[5] = f2bf(b.y); o[6] = f2bf(b.z); o[7] = f2bf(b.w);
  *(ushort8*)(xb + i) = o;
}

// -------- transpose+convert weight: src f32 [R,Cc] -> dst bf16 [Cpad][Rpad], dst[c][r]=src[r][c] (0 pad) --------
__global__ __launch_bounds__(256) void k_tconv(const float* __restrict__ src, u16* __restrict__ dst,
                                               int R, int Cc, int Rpad) {
  __shared__ float sm[32][33];
  int tx = threadIdx.x & 31, ty = threadIdx.x >> 5;
  int r0 = blockIdx.x * 32, c0 = blockIdx.y * 32;
#pragma unroll
  for (int i = 0; i < 4; i++) {
    int r = r0 + ty + 8 * i;
    int c = c0 + tx;
    sm[ty + 8 * i][tx] = (r < R && c < Cc) ? src[(size_t)r * Cc + c] : 0.f;
  }
  __syncthreads();
#pragma unroll
  for (int i = 0; i < 4; i++) {
    int c = c0 + ty + 8 * i;
    dst[(size_t)c * Rpad + r0 + tx] = f2bf(sm[tx][ty + 8 * i]);
  }
}

// ---------------- gate = 2*sigmoid(x[:, :32] @ w_ve_gate) ----------------
__global__ __launch_bounds__(256) void k_gate(const float* __restrict__ x, const float* __restrict__ wg,
                                              float* __restrict__ gate) {
  int idx = blockIdx.x * 256 + threadIdx.x; // m*16 + h
  int m = idx >> 4, h = idx & 15;
  const float* xr = x + (size_t)m * 2048;
  float s = 0.f;
#pragma unroll
  for (int j = 0; j < 32; j++) s += xr[j] * wg[j * 16 + h];
  gate[idx] = 2.f / (1.f + __expf(-s));
}

// ---------------- generic GEMM: C[M,N] = A[M,K] @ BT[N,K]^T, bf16 in, f32 accum, OT out ----------------
template <typename OT>
__global__ __launch_bounds__(256) void k_gemm_bt(const u16* __restrict__ A, const u16* __restrict__ BT,
                                                 OT* __restrict__ C, int M, int N, int K) {
  __shared__ __align__(16) u16 As[64][40];
  __shared__ __align__(16) u16 Bs[64][40];
  int t = threadIdx.x;
  int wid = t >> 6, lane = t & 63;
  int wr = (wid >> 1) * 32, wc = (wid & 1) * 32;
  int m0 = blockIdx.y * 64, n0 = blockIdx.x * 64;
  int lrow = t >> 2, lk = (t & 3) * 8;
  const u16* Ag = A + (size_t)(m0 + lrow) * K + lk;
  const u16* Bg = BT + (size_t)(n0 + lrow) * K + lk;
  f32x4 acc00 = {0,0,0,0}, acc01 = {0,0,0,0}, acc10 = {0,0,0,0}, acc11 = {0,0,0,0};
  int fr = lane & 15, fo = (lane >> 4) * 8;
  for (int k0 = 0; k0 < K; k0 += 32) {
    *(ushort8*)&As[lrow][lk] = *(const ushort8*)(Ag + k0);
    *(ushort8*)&Bs[lrow][lk] = *(const ushort8*)(Bg + k0);
    __syncthreads();
    bf16x8 a0 = *(const bf16x8*)&As[wr + fr][fo];
    bf16x8 a1 = *(const bf16x8*)&As[wr + 16 + fr][fo];
    bf16x8 b0 = *(const bf16x8*)&Bs[wc + fr][fo];
    bf16x8 b1 = *(const bf16x8*)&Bs[wc + 16 + fr][fo];
    acc00 = __builtin_amdgcn_mfma_f32_16x16x32_bf16(a0, b0, acc00, 0, 0, 0);
    acc01 = __builtin_amdgcn_mfma_f32_16x16x32_bf16(a0, b1, acc01, 0, 0, 0);
    acc10 = __builtin_amdgcn_mfma_f32_16x16x32_bf16(a1, b0, acc10, 0, 0, 0);
    acc11 = __builtin_amdgcn_mfma_f32_16x16x32_bf16(a1, b1, acc11, 0, 0, 0);
    __syncthreads();
  }
  int cr = (lane >> 4) * 4, cc = lane & 15;
#pragma unroll
  for (int r = 0; r < 4; r++) {
    size_t row0 = (size_t)(m0 + wr + cr + r);
    size_t row1 = row0 + 16;
    st_out(&C[row0 * N + n0 + wc + cc],      acc00[r]);
    st_out(&C[row0 * N + n0 + wc + 16 + cc], acc01[r]);
    st_out(&C[row1 * N + n0 + wc + cc],      acc10[r]);
    st_out(&C[row1 * N + n0 + wc + 16 + cc], acc11[r]);
  }
}

// ---------------- build K: concat(k_nope, rope(k_rope)), rmsnorm, -> kf[b][h][t][128] bf16 ----------------
__global__ __launch_bounds__(256) void k_build_k(const u16* __restrict__ kv, const u16* __restrict__ kr,
                                                 const float* __restrict__ cosp, const float* __restrict__ sinp,
                                                 u16* __restrict__ kf) {
  int wid = threadIdx.x >> 6, lane = threadIdx.x & 63;
  int idx = blockIdx.x * 4 + wid; // m*16 + h
  int m = idx >> 4, h = idx & 15;
  int d0 = lane * 2;
  float v[2];
#pragma unroll
  for (int e = 0; e < 2; e++) {
    int d = d0 + e;
    float val;
    if (d < 64) {
      val = bf2f(kv[(size_t)m * 3072 + h * 192 + d]);
    } else {
      int dd = d - 64, i = dd & 31;
      float c = cosp[m * 32 + i], s = sinp[m * 32 + i];
      float x1 = bf2f(kr[(size_t)m * 64 + i]), x2 = bf2f(kr[(size_t)m * 64 + 32 + i]);
      val = (dd < 32) ? (x1 * c + x2 * s) : (x2 * c - x1 * s);
    }
    v[e] = val;
  }
  float ss = v[0] * v[0] + v[1] * v[1];
#pragma unroll
  for (int o = 1; o < 64; o <<= 1) ss += __shfl_xor(ss, o, 64);
  float rms = rsqrtf(ss * (1.f / 128.f) + 1.1920929e-7f);
  int b = m >> 11, tt = m & 2047;
  size_t base = ((size_t)(b * NHEAD + h) * TSEQ + tt) * 128 + d0;
  kf[base] = f2bf(v[0] * rms);
  kf[base + 1] = f2bf(v[1] * rms);
}

// ---------------- build Q: concat(q_nope, rope(q_rope)), rmsnorm * 1/sqrt(128), -> qf[b][h][t][128] bf16 ----------------
// NOTE: attention scale is folded in here so k_attn's hot loop has zero scale multiplies.
__global__ __launch_bounds__(256) void k_build_q(const u16* __restrict__ qr,
                                                 const float* __restrict__ cosp, const float* __restrict__ sinp,
                                                 u16* __restrict__ qf) {
  int wid = threadIdx.x >> 6, lane = threadIdx.x & 63;
  int idx = blockIdx.x * 4 + wid; // m*16 + h
  int m = idx >> 4, h = idx & 15;
  size_t bin = (size_t)m * 2048 + h * 128;
  int d0 = lane * 2;
  float v[2];
#pragma unroll
  for (int e = 0; e < 2; e++) {
    int d = d0 + e;
    float val;
    if (d < 64) {
      val = bf2f(qr[bin + d]);
    } else {
      int dd = d - 64, i = dd & 31;
      float c = cosp[m * 32 + i], s = sinp[m * 32 + i];
      float x1 = bf2f(qr[bin + 64 + i]), x2 = bf2f(qr[bin + 96 + i]);
      val = (dd < 32) ? (x1 * c + x2 * s) : (x2 * c - x1 * s);
    }
    v[e] = val;
  }
  float ss = v[0] * v[0] + v[1] * v[1];
#pragma unroll
  for (int o = 1; o < 64; o <<= 1) ss += __shfl_xor(ss, o, 64);
  float rms = rsqrtf(ss * (1.f / 128.f) + 1.1920929e-7f) * 0.08838834764831845f; // rms * 1/sqrt(128)
  int b = m >> 11, tt = m & 2047;
  size_t base = ((size_t)(b * NHEAD + h) * TSEQ + tt) * 128 + d0;
  qf[base] = f2bf(v[0] * rms);
  qf[base + 1] = f2bf(v[1] * rms);
}

// ---------------- build V: v = kv_v + gate*ve, transpose -> vt[b][h][128][t] bf16 ----------------
__global__ __launch_bounds__(256) void k_build_v(const u16* __restrict__ kv, const float* __restrict__ ve,
                                                 const float* __restrict__ gate, u16* __restrict__ vt) {
  __shared__ __align__(16) char sm[128 * 128]; // [128 d][64 t] u16, XOR-swizzled rows
  int bh = blockIdx.x >> 5, t0 = (blockIdx.x & 31) * 64;
  int b = bh >> 4, h = bh & 15;
  int tt = threadIdx.x >> 2, dp = (threadIdx.x & 3) * 32;
  int m = b * TSEQ + t0 + tt;
  float g = gate[m * 16 + h];
  const u16* kvp = kv + (size_t)m * 3072 + h * 192 + 64 + dp;
  const float* vep = ve + (size_t)m * 2048 + h * 128 + dp;
  ushort8 kvv[4];
  float4 vev[8];
#pragma unroll
  for (int u = 0; u < 4; u++) kvv[u] = *(const ushort8*)(kvp + u * 8);
#pragma unroll
  for (int u = 0; u < 8; u++) vev[u] = *(const float4*)(vep + u * 4);
#pragma unroll
  for (int j = 0; j < 32; j++) {
    float vvf = ((const float*)&vev[j >> 2])[j & 3];
    float v = bf2f(kvv[j >> 3][j & 7]) + g * vvf;
    int row = dp + j;
    int a = row * 128 + tt * 2;
    *(u16*)(sm + (a ^ ((row & 7) << 4))) = f2bf(v);
  }
  __syncthreads();
  int d = threadIdx.x >> 1, tp = (threadIdx.x & 1) * 32;
  u16* dst = vt + ((size_t)bh * 128 + d) * TSEQ + t0 + tp;
#pragma unroll
  for (int j = 0; j < 32; j += 8) {
    int a = d * 128 + (tp + j) * 2;
    *(ushort8*)(dst + j) = *(const ushort8*)(sm + (a ^ ((d & 7) << 4)));
  }
}

// ---------------- flash attention: 1 wave per 64-thread block, 16-row q tile, KT=64 ----------------
// Heavy-first block ordering (qt reversed); split loop: nfull unmasked tiles + exactly 1 masked tile.
// Q is pre-scaled by 1/sqrt(128) in k_build_q.
__global__ __launch_bounds__(64) void k_attn(const u16* __restrict__ qf, const u16* __restrict__ kf,
                                             const u16* __restrict__ vt, u16* __restrict__ y) {
  __shared__ u16 plds[1024]; // 16 rows x 64 cols (byte addr: row*128 + col*2), XOR-swizzled
  int lane = threadIdx.x;
  int bh = blockIdx.x & 31;          // 32 (b,h) pairs
  int qt = 127 - (blockIdx.x >> 5);  // heavy tasks dispatched first
  int q0 = qt * 16;
  const u16* qp = qf + (size_t)bh * TSEQ * 128;
  const u16* kp = kf + (size_t)bh * TSEQ * 128;
  const u16* vp = vt + (size_t)bh * 128 * TSEQ;
  int fr = lane & 15, fo = (lane >> 4) * 8;
  bf16x8 qfr[4];
#pragma unroll
  for (int kc = 0; kc < 4; kc++)
    qfr[kc] = *(const bf16x8*)(qp + (size_t)(q0 + fr) * 128 + kc * 32 + fo);
  f32x4 oacc[8];
#pragma unroll
  for (int nd = 0; nd < 8; nd++) oacc[nd] = (f32x4){0, 0, 0, 0};
  float mrow[4] = {-1e30f, -1e30f, -1e30f, -1e30f};
  float srow[4] = {0, 0, 0, 0};
  int qgb = q0 + (lane >> 4) * 4;
  int nfull = (q0 + 1) >> 6; // tiles with kt0+63 <= q0 need no causal mask
  for (int it = 0; it <= nfull; it++) {
    int kt0 = it << 6;
    bool maskit = (it == nfull); // exactly one boundary tile per task
    f32x4 sacc[4];
#pragma unroll
    for (int s = 0; s < 4; s++) sacc[s] = (f32x4){0, 0, 0, 0};
#pragma unroll
    for (int s = 0; s < 4; s++) {
      const u16* krow = kp + (size_t)(kt0 + s * 16 + fr) * 128 + fo;
#pragma unroll
      for (int kc = 0; kc < 4; kc++) {
        bf16x8 kfr = *(const bf16x8*)(krow + kc * 32);
        sacc[s] = __builtin_amdgcn_mfma_f32_16x16x32_bf16(qfr[kc], kfr, sacc[s], 0, 0, 0);
      }
    }
    float fsc[4];
#pragma unroll
    for (int r = 0; r < 4; r++) {
      int qrow = qgb + r;
      float mx = -3e38f;
      if (maskit) {
#pragma unroll
        for (int s = 0; s < 4; s++) {
          int key = kt0 + s * 16 + fr;
          float v = (key <= qrow) ? sacc[s][r] : -3e38f;
          sacc[s][r] = v;
          mx = fmaxf(mx, v);
        }
      } else {
#pragma unroll
        for (int s = 0; s < 4; s++) mx = fmaxf(mx, sacc[s][r]);
      }
#pragma unroll
      for (int o = 1; o < 16; o <<= 1) mx = fmaxf(mx, __shfl_xor(mx, o, 64));
      float mn = fmaxf(mrow[r], mx);
      float f = __expf(mrow[r] - mn);
      mrow[r] = mn;
      float rs = 0.f;
#pragma unroll
      for (int s = 0; s < 4; s++) {
        float p = __expf(sacc[s][r] - mn);
        sacc[s][r] = p;
        rs += p;
      }
#pragma unroll
      for (int o = 1; o < 16; o <<= 1) rs += __shfl_xor(rs, o, 64);
      srow[r] = srow[r] * f + rs;
      fsc[r] = f;
    }
#pragma unroll
    for (int nd = 0; nd < 8; nd++)
#pragma unroll
      for (int r = 0; r < 4; r++) oacc[nd][r] *= fsc[r];
    // P -> LDS (bf16 stored as u16, XOR-swizzled byte addressing)
    int lrb = (lane >> 4) * 4;
#pragma unroll
    for (int r = 0; r < 4; r++) {
      int row = lrb + r;
#pragma unroll
      for (int s = 0; s < 4; s++) {
        int a = row * 128 + (s * 16 + fr) * 2;
        plds[(a ^ ((row & 7) << 4)) >> 1] = f2bf(sacc[s][r]);
      }
    }
#pragma unroll
    for (int kc2 = 0; kc2 < 2; kc2++) {
      bf16x8 pa;
#pragma unroll
      for (int j = 0; j < 8; j++) {
        int a = fr * 128 + (kc2 * 32 + fo + j) * 2;
        u16 raw = plds[(a ^ ((fr & 7) << 4)) >> 1];
        union { u16 u; __bf16 b; } cv; cv.u = raw;
        pa[j] = cv.b;
      }
#pragma unroll
      for (int nd = 0; nd < 8; nd++) {
        const u16* vrow = vp + (size_t)(nd * 16 + fr) * TSEQ + kt0 + kc2 * 32 + fo;
        bf16x8 vfr = *(const bf16x8*)vrow;
        oacc[nd] = __builtin_amdgcn_mfma_f32_16x16x32_bf16(pa, vfr, oacc[nd], 0, 0, 0);
      }
    }
  }
  int b = bh >> 4, h = bh & 15;
  float inv[4];
#pragma unroll
  for (int r = 0; r < 4; r++) inv[r] = 1.f / srow[r];
#pragma unroll
  for (int nd = 0; nd < 8; nd++) {
#pragma unroll
    for (int r = 0; r < 4; r++) {
      int qrow = qgb + r;
      size_t offo = ((size_t)(b * TSEQ + qrow)) * 2048 + h * 128 + nd * 16 + fr;
      y[offo] = f2bf(oacc[nd][r] * inv[r]);
    }
  }
}

extern "C" void kernel_launch(void* const* d_in, const int* in_sizes, int n_in,
                              void* d_out, int out_size, void* d_ws, size_t ws_size,
                              hipStream_t stream) {
  (void)in_sizes; (void)n_in; (void)out_size; (void)ws_size;
  const float* x      = (const float*)d_in[0];
  const float* ve     = (const float*)d_in[1];
  const float* cosp   = (const float*)d_in[2];
  const float* sinp   = (const float*)d_in[3];
  const float* w_dkv  = (const float*)d_in[4];
  const float* w_ukv  = (const float*)d_in[5];
  const float* w_kr   = (const float*)d_in[6];
  const float* w_dq   = (const float*)d_in[7];
  const float* w_q    = (const float*)d_in[8];
  const float* w_cp   = (const float*)d_in[9];
  const float* w_vg   = (const float*)d_in[10];
  float* out = (float*)d_out;   // reference output dtype is float32

  char* ws = (char*)d_ws;
  size_t off = 0;
  auto alloc = [&](size_t bytes) -> char* {
    char* p = ws + off;
    off += (bytes + 255) & ~(size_t)255;
    return p;
  };
  u16* xb     = (u16*)alloc(4096ull * 2048 * 2);
  u16* wdkvT  = (u16*)alloc(704ull * 2048 * 2);
  u16* wukvT  = (u16*)alloc(3072ull * 704 * 2);
  u16* wkrT   = (u16*)alloc(64ull * 2048 * 2);
  u16* wdqT   = (u16*)alloc(704ull * 2048 * 2);
  u16* wqT    = (u16*)alloc(2048ull * 704 * 2);
  u16* wcpT   = (u16*)alloc(2048ull * 2048 * 2);
  u16* ckv    = (u16*)alloc(4096ull * 704 * 2);
  u16* kvb    = (u16*)alloc(4096ull * 3072 * 2);
  u16* q1b    = (u16*)alloc(4096ull * 704 * 2);
  u16* qrawb  = (u16*)alloc(4096ull * 2048 * 2);
  u16* krb    = (u16*)alloc(4096ull * 64 * 2);
  float* gateb = (float*)alloc(4096ull * 16 * 4);
  u16* qfb    = (u16*)alloc(2ull * 16 * 2048 * 128 * 2);
  u16* kfb    = (u16*)alloc(2ull * 16 * 2048 * 128 * 2);
  u16* vtb    = (u16*)alloc(2ull * 16 * 128 * 2048 * 2);
  u16* yb = xb; // alias: x_bf dead after q1/k_rope/gate GEMMs

  // 1. conversions
  k_conv_x<<<dim3(4096), dim3(256), 0, stream>>>(x, xb);
  k_tconv<<<dim3(64, 22), dim3(256), 0, stream>>>(w_dkv, wdkvT, 2048, 672, 2048);
  k_tconv<<<dim3(22, 96), dim3(256), 0, stream>>>(w_ukv, wukvT, 672, 3072, 704);
  k_tconv<<<dim3(64, 2),  dim3(256), 0, stream>>>(w_kr,  wkrT,  2048, 64, 2048);
  k_tconv<<<dim3(64, 22), dim3(256), 0, stream>>>(w_dq,  wdqT,  2048, 672, 2048);
  k_tconv<<<dim3(22, 64), dim3(256), 0, stream>>>(w_q,   wqT,   672, 2048, 704);
  k_tconv<<<dim3(64, 64), dim3(256), 0, stream>>>(w_cp,  wcpT,  2048, 2048, 2048);
  k_gate<<<dim3(256), dim3(256), 0, stream>>>(x, w_vg, gateb);

  // 2. projection GEMMs (bf16 out)
  k_gemm_bt<u16><<<dim3(11, 64), dim3(256), 0, stream>>>(xb,  wdkvT, ckv,   4096, 704, 2048);
  k_gemm_bt<u16><<<dim3(48, 64), dim3(256), 0, stream>>>(ckv, wukvT, kvb,   4096, 3072, 704);
  k_gemm_bt<u16><<<dim3(1, 64),  dim3(256), 0, stream>>>(xb,  wkrT,  krb,   4096, 64, 2048);
  k_gemm_bt<u16><<<dim3(11, 64), dim3(256), 0, stream>>>(xb,  wdqT,  q1b,   4096, 704, 2048);
  k_gemm_bt<u16><<<dim3(32, 64), dim3(256), 0, stream>>>(q1b, wqT,   qrawb, 4096, 2048, 704);

  // 3. build q/k/v
  k_build_k<<<dim3(16384), dim3(256), 0, stream>>>(kvb, krb, cosp, sinp, kfb);
  k_build_q<<<dim3(16384), dim3(256), 0, stream>>>(qrawb, cosp, sinp, qfb);
  k_build_v<<<dim3(1024), dim3(256), 0, stream>>>(kvb, ve, gateb, vtb);

  // 4. attention -> y (aliases xb): 4096 blocks x 1 wave, heavy-first
  k_attn<<<dim3(4096), dim3(64), 0, stream>>>(qfb, kfb, vtb, yb);

  // 5. output projection (f32 out -> d_out)
  k_gemm_bt<float><<<dim3(32, 64), dim3(256), 0, stream>>>(yb, wcpT, out, 4096, 2048, 2048);
}